// Round 5
// baseline (140.895 us; speedup 1.0000x reference)
//
#include <hip/hip_runtime.h>
#include <math.h>

// NeuralSplineFourierFilterNNX — tiny MLP on scalar `a` parameterizes a
// degree-3 B-spline; evaluate at 256^3 fp32 grid points.
//
// SINGLE fused kernel (2048x256): every block redundantly computes the spline
// setup (~2K FLOPs) in its own LDS, then streams x.
// R5: latency-bound fix (R4 evidence: 45us, 28% HBM, 38% VALU, VGPR=32 ->
// zero cross-iteration MLP). Manual 4x unroll with upfront nontemporal loads
// (64B/thread in flight, 16 independent LDS gather chains), boundaries forced
// to SGPRs via readfirstlane, plain stores (fill kernels hit 6.4TB/s with
// plain stores). Target ~28-33us kernel.

typedef float fvec4 __attribute__((ext_vector_type(4)));  // legal for nontemporal builtins

__device__ __forceinline__ float deboor_eval(float x, int k, const float* t, const float* c) {
    float d[4];
#pragma unroll
    for (int j = 0; j < 4; ++j) d[j] = c[j + k - 3];
#pragma unroll
    for (int r = 1; r <= 3; ++r) {
#pragma unroll
        for (int j = 3; j >= 1; --j) {
            if (j < r) continue;   // constant-folds under unroll
            float tlo = t[j + k - 3];
            float thi = t[j + 1 + k - r];
            float al = (x - tlo) / (thi - tlo);
            d[j] = (1.0f - al) * d[j - 1] + al * d[j];
        }
    }
    return d[3];
}

#define K_INV_SQRT3 0.57735026918962576f
#define K_XMAX      (1.0f - 1e-4f)

__device__ __forceinline__ fvec4 eval_vec(fvec4 xv, const float* bb,
                                          const fvec4* sC, const float* sStart) {
    float xc[4]; int sg[4];
#pragma unroll
    for (int e = 0; e < 4; ++e) {
        float v = fminf(fmaxf(xv[e] * K_INV_SQRT3, 0.0f), K_XMAX);  // v_med3
        xc[e] = v;
        int si = 0;
#pragma unroll
        for (int j = 0; j < 14; ++j) si += (v >= bb[j]) ? 1 : 0;    // searchsorted-right
        sg[e] = si;
    }
    fvec4 c[4]; float st[4];
#pragma unroll
    for (int e = 0; e < 4; ++e) {       // batch the LDS gathers -> 4 chains in flight
        c[e]  = sC[sg[e]];              // ds_read_b128
        st[e] = sStart[sg[e]];          // ds_read_b32
    }
    fvec4 r;
#pragma unroll
    for (int e = 0; e < 4; ++e) {
        float u = xc[e] - st[e];
        r[e] = fmaf(fmaf(fmaf(c[e].w, u, c[e].z), u, c[e].y), u, c[e].x);
    }
    return r;
}

__global__ __launch_bounds__(256) void spline_fused_kernel(
    const float* __restrict__ x,
    const float* __restrict__ a,  const float* __restrict__ W1, const float* __restrict__ b1,
    const float* __restrict__ W2, const float* __restrict__ b2,
    const float* __restrict__ Ww, const float* __restrict__ bw,
    const float* __restrict__ Wk, const float* __restrict__ bk,
    float* __restrict__ out, int n)
{
    // ---- per-block redundant setup (~2K FLOPs, weights ~2.5 KB from L2/L3) ----
    __shared__ float net1[32], net2[32], cpt[18], kl[15], ak[22];
    __shared__ float sBB[14];          // segment-search boundaries: knots 1..14
    __shared__ float sStart[16];       // segment start = knot[s]
    __shared__ fvec4 sC[16];           // c0..c3 per segment (one ds_read_b128)

    int t = threadIdx.x;

    if (t < 32) net1[t] = sinf(a[0] * W1[t] + b1[t]);
    __syncthreads();

    if (t < 32) {
        float s = b2[t];
#pragma unroll
        for (int i = 0; i < 32; ++i) s += net1[i] * W2[i * 32 + t];
        net2[t] = sinf(s);
    }
    __syncthreads();

    if (t < 17) {                      // control points: w = concat([0], net@Ww+bw)
        float s = bw[t];
#pragma unroll
        for (int i = 0; i < 32; ++i) s += net2[i] * Ww[i * 17 + t];
        cpt[t + 1] = s;
    }
    if (t == 63) cpt[0] = 0.0f;
    if (t >= 32 && t < 47) {           // knot logits
        int j = t - 32;
        float s = bk[j];
#pragma unroll
        for (int i = 0; i < 32; ++i) s += net2[i] * Wk[i * 15 + j];
        kl[j] = s;
    }
    __syncthreads();

    if (t == 0) {                      // softmax + cumsum -> padded knot vector ak[22]
        float m = kl[0];
        for (int j = 1; j < 15; ++j) m = fmaxf(m, kl[j]);
        float e[15], sum = 0.0f;
        for (int j = 0; j < 15; ++j) { e[j] = expf(kl[j] - m); sum += e[j]; }
        float inv = 1.0f / sum;
        ak[0] = ak[1] = ak[2] = 0.0f;
        ak[3] = 0.0f;                  // prepended zero knot
        float cum = 0.0f;
        for (int j = 0; j < 15; ++j) { cum += e[j]; ak[4 + j] = cum * inv; }
        ak[19] = ak[20] = ak[21] = 1.0f;
    }
    __syncthreads();

    if (t < 14) sBB[t] = ak[4 + t];
    if (t < 15) {                      // segment s: knot-index k = s+3, x in [ak[k], ak[k+1])
        int k = t + 3;
        float t0 = ak[k], t1 = ak[k + 1];
        float dl = (t1 - t0) * (1.0f / 3.0f);
        float f0 = deboor_eval(t0,              k, ak, cpt);
        float f1 = deboor_eval(t0 + dl,         k, ak, cpt);
        float f2 = deboor_eval(t0 + 2.0f * dl,  k, ak, cpt);
        float f3 = deboor_eval(t0 + 3.0f * dl,  k, ak, cpt);
        // Newton divided differences (equispaced, spacing dl) -> power basis in u = x - t0
        float idl  = 1.0f / dl;
        float g01  = (f1 - f0) * idl, g12 = (f2 - f1) * idl, g23 = (f3 - f2) * idl;
        float h012 = (g12 - g01) * (0.5f * idl), h123 = (g23 - g12) * (0.5f * idl);
        float q    = (h123 - h012) * (idl * (1.0f / 3.0f));
        fvec4 c;
        c.x = f0;                                    // c0
        c.y = g01 - dl * h012 + 2.0f * dl * dl * q;  // c1
        c.z = h012 - 3.0f * dl * q;                  // c2
        c.w = q;                                     // c3
        sStart[t] = t0;
        sC[t] = c;
    }
    __syncthreads();

    // ---- boundaries into SGPRs (wave-uniform) ----
    float bb[14];
#pragma unroll
    for (int j = 0; j < 14; ++j)
        bb[j] = __int_as_float(__builtin_amdgcn_readfirstlane(__float_as_int(sBB[j])));

    // ---- streaming eval: 4x unrolled, loads upfront for cross-iteration MLP ----
    int n4 = n >> 2;
    int gtid = blockIdx.x * blockDim.x + t;
    int stride = gridDim.x * blockDim.x;
    const fvec4* x4 = (const fvec4*)x;
    fvec4* o4 = (fvec4*)out;

    int i = gtid;
    for (; i + 3 * stride < n4; i += 4 * stride) {
        fvec4 v0 = __builtin_nontemporal_load(&x4[i]);
        fvec4 v1 = __builtin_nontemporal_load(&x4[i +     stride]);
        fvec4 v2 = __builtin_nontemporal_load(&x4[i + 2 * stride]);
        fvec4 v3 = __builtin_nontemporal_load(&x4[i + 3 * stride]);
        o4[i]              = eval_vec(v0, bb, sC, sStart);
        o4[i +     stride] = eval_vec(v1, bb, sC, sStart);
        o4[i + 2 * stride] = eval_vec(v2, bb, sC, sStart);
        o4[i + 3 * stride] = eval_vec(v3, bb, sC, sStart);
    }
    for (; i < n4; i += stride) {
        fvec4 v = __builtin_nontemporal_load(&x4[i]);
        o4[i] = eval_vec(v, bb, sC, sStart);
    }
    // generic scalar tail (n % 4 != 0); no-op for 256^3
    for (int k2 = (n4 << 2) + gtid; k2 < n; k2 += stride) {
        float xc = fminf(fmaxf(x[k2] * K_INV_SQRT3, 0.0f), K_XMAX);
        int s = 0;
#pragma unroll
        for (int j = 0; j < 14; ++j) s += (xc >= bb[j]) ? 1 : 0;
        fvec4 c = sC[s];
        float u = xc - sStart[s];
        out[k2] = fmaf(fmaf(fmaf(c.w, u, c.z), u, c.y), u, c.x);
    }
}

extern "C" void kernel_launch(void* const* d_in, const int* in_sizes, int n_in,
                              void* d_out, int out_size, void* d_ws, size_t ws_size,
                              hipStream_t stream)
{
    const float* x  = (const float*)d_in[0];
    const float* a  = (const float*)d_in[1];
    const float* W1 = (const float*)d_in[2];
    const float* b1 = (const float*)d_in[3];
    const float* W2 = (const float*)d_in[4];
    const float* b2 = (const float*)d_in[5];
    const float* Ww = (const float*)d_in[6];
    const float* bw = (const float*)d_in[7];
    const float* Wk = (const float*)d_in[8];
    const float* bk = (const float*)d_in[9];
    float* out = (float*)d_out;

    spline_fused_kernel<<<2048, 256, 0, stream>>>(
        x, a, W1, b1, W2, b2, Ww, bw, Wk, bk, out, out_size);
}